// Round 16
// baseline (335.286 us; speedup 1.0000x reference)
//
#include <hip/hip_runtime.h>
#include <cstdint>
#include <cstddef>

typedef unsigned short u16;
typedef short short8 __attribute__((ext_vector_type(8)));
typedef float f32x4 __attribute__((ext_vector_type(4)));

#define B_   2
#define T_   2048
#define H_   16
#define HID_ 2048
#define DQK_ 192
#define DV_  128
#define AW_  3072   // fused a-proj output width (q_a 1536 | kv_raw 1536)

__device__ __forceinline__ float bf2f(u16 u) {
  unsigned int v = ((unsigned int)u) << 16;
  return __builtin_bit_cast(float, v);
}
__device__ __forceinline__ u16 f2bf(float f) {
  unsigned int u = __builtin_bit_cast(unsigned int, f);
  u += 0x7fff + ((u >> 16) & 1);   // round-to-nearest-even
  return (u16)(u >> 16);
}
__device__ __forceinline__ void load_lds16(const void* g, void* l) {
  __builtin_amdgcn_global_load_lds((const __attribute__((address_space(1))) void*)g,
                                   (__attribute__((address_space(3))) void*)l, 16, 0, 0);
}

// ---------------- cast f32 -> bf16 (8 elems/thread) ----------------
__global__ __launch_bounds__(256) void cast_f32_bf16(const float* __restrict__ x,
                                                     u16* __restrict__ y) {
  size_t i = ((size_t)blockIdx.x * 256 + threadIdx.x) * 8;
  float4 a = *(const float4*)&x[i];
  float4 b = *(const float4*)&x[i + 4];
  u16 r[8];
  r[0] = f2bf(a.x); r[1] = f2bf(a.y); r[2] = f2bf(a.z); r[3] = f2bf(a.w);
  r[4] = f2bf(b.x); r[5] = f2bf(b.y); r[6] = f2bf(b.z); r[7] = f2bf(b.w);
  *(uint4*)&y[i] = *(const uint4*)&r[0];
}

// ---------------- W (K x N) f32  ->  Wt (N x K) bf16 ----------------
__global__ __launch_bounds__(256) void transpose_cast_k(const float* __restrict__ W,
                                                        u16* __restrict__ Wt,
                                                        int K, int N) {
  __shared__ u16 tile[32][33];
  int n0 = blockIdx.x * 32, k0 = blockIdx.y * 32;
  int tx = threadIdx.x & 31, ty = threadIdx.x >> 5;
#pragma unroll
  for (int i = 0; i < 32; i += 8)
    tile[ty + i][tx] = f2bf(W[(size_t)(k0 + ty + i) * N + n0 + tx]);
  __syncthreads();
#pragma unroll
  for (int i = 0; i < 32; i += 8)
    Wt[(size_t)(n0 + ty + i) * K + k0 + tx] = tile[tx][ty + i];
}

// ---------------- dual RMSNorm: q_a (L=1536) -> out1, kv latent (L=512) -> out2 ----------------
__global__ __launch_bounds__(256) void rmsnorm_dual(const u16* __restrict__ qa,
                                                    const float* __restrict__ w1,
                                                    u16* __restrict__ out1,
                                                    const float* __restrict__ w2,
                                                    u16* __restrict__ out2) {
  __shared__ float red[4];
  const int row = blockIdx.x, tid = threadIdx.x;
  {
    const u16* x = qa + (size_t)row * AW_;
    float ss = 0.f;
    for (int i = tid * 8; i < 1536; i += 2048) {
      uint4 v = *(const uint4*)&x[i];
      const u16* p = (const u16*)&v;
#pragma unroll
      for (int e = 0; e < 8; ++e) { float f = bf2f(p[e]); ss += f * f; }
    }
#pragma unroll
    for (int m = 32; m >= 1; m >>= 1) ss += __shfl_xor(ss, m);
    if ((tid & 63) == 0) red[tid >> 6] = ss;
    __syncthreads();
    ss = red[0] + red[1] + red[2] + red[3];
    float inv = rsqrtf(ss / 1536.f + 1e-6f);
    u16* o = out1 + (size_t)row * 1536;
    for (int i = tid * 8; i < 1536; i += 2048) {
      uint4 v = *(const uint4*)&x[i];
      const u16* p = (const u16*)&v;
      u16 r8[8];
#pragma unroll
      for (int e = 0; e < 8; ++e) r8[e] = f2bf(bf2f(p[e]) * inv * w1[i + e]);
      *(uint4*)&o[i] = *(const uint4*)&r8[0];
    }
  }
  __syncthreads();
  {
    const u16* x = qa + (size_t)row * AW_ + 1536;
    float ss = 0.f;
    for (int i = tid * 8; i < 512; i += 2048) {
      uint4 v = *(const uint4*)&x[i];
      const u16* p = (const u16*)&v;
#pragma unroll
      for (int e = 0; e < 8; ++e) { float f = bf2f(p[e]); ss += f * f; }
    }
#pragma unroll
    for (int m = 32; m >= 1; m >>= 1) ss += __shfl_xor(ss, m);
    if ((tid & 63) == 0) red[tid >> 6] = ss;
    __syncthreads();
    ss = red[0] + red[1] + red[2] + red[3];
    float inv = rsqrtf(ss / 512.f + 1e-6f);
    u16* o = out2 + (size_t)row * 512;
    for (int i = tid * 8; i < 512; i += 2048) {
      uint4 v = *(const uint4*)&x[i];
      const u16* p = (const u16*)&v;
      u16 r8[8];
#pragma unroll
      for (int e = 0; e < 8; ++e) r8[e] = f2bf(bf2f(p[e]) * inv * w2[i + e]);
      *(uint4*)&o[i] = *(const uint4*)&r8[0];
    }
  }
}

// ---------------- GEMM 256x256 (4-phase), BK=64, 512 thr / 8 waves ----------------
// Verified r14/r15. EPI: 1 = bf16; 3 = bf16 * softmax scale; 2 = bf16 + Vt scatter.
template <int EPI>
__global__ __launch_bounds__(512) void gemm256(const u16* __restrict__ A,
                                               const u16* __restrict__ Bt,
                                               void* __restrict__ Cout,
                                               u16* __restrict__ Vt2,
                                               int M, int N, int K) {
  __shared__ u16 As[2][256 * 64];   // 64 KB
  __shared__ u16 Bs[2][256 * 64];   // 64 KB
  const int nbx = N >> 8;
  const int bx = blockIdx.x % nbx, by = blockIdx.x / nbx;
  const int m0 = by << 8, n0 = bx << 8;
  const int tid = threadIdx.x, w = tid >> 6, lane = tid & 63;
  const int wm = w >> 2, wn = w & 3;
  const int llo = lane & 15, lhi = lane >> 4;
  f32x4 acc[8][4] = {};

  const u16* srcp[8];
  int dsto[8];
#pragma unroll
  for (int jl = 0; jl < 2; ++jl) {
    int c = jl * 512 + tid;
    int i = c >> 3, sl = c & 7;
    { int r = ((i >> 6) << 7) + (i & 63);
      srcp[jl] = A + (size_t)(m0 + r) * K + ((sl ^ (r & 7)) << 3);
      dsto[jl] = (r * 8 + sl) * 8; }
    { int r = ((i >> 5) << 6) + (i & 31);
      srcp[2 + jl] = Bt + (size_t)(n0 + r) * K + ((sl ^ (r & 7)) << 3);
      dsto[2 + jl] = (r * 8 + sl) * 8; }
    { int r = ((i >> 5) << 6) + 32 + (i & 31);
      srcp[4 + jl] = Bt + (size_t)(n0 + r) * K + ((sl ^ (r & 7)) << 3);
      dsto[4 + jl] = (r * 8 + sl) * 8; }
    { int r = ((i >> 6) << 7) + 64 + (i & 63);
      srcp[6 + jl] = A + (size_t)(m0 + r) * K + ((sl ^ (r & 7)) << 3);
      dsto[6 + jl] = (r * 8 + sl) * 8; }
  }
#define STG(j, kt, buf)                                                        \
  load_lds16(srcp[j] + (size_t)(kt) * 64,                                      \
             ((j) < 2 || (j) >= 6) ? &As[(buf)][dsto[j]] : &Bs[(buf)][dsto[j]])

  auto rdA = [&](int buf, int mi, int ks) {
    int r = wm * 128 + mi * 16 + llo;
    return *(const short8*)&As[buf][r * 64 + (((ks * 4 + lhi) ^ (r & 7)) << 3)];
  };
  auto rdB = [&](int buf, int nj, int ks) {
    int r = wn * 64 + nj * 16 + llo;
    return *(const short8*)&Bs[buf][r * 64 + (((ks * 4 + lhi) ^ (r & 7)) << 3)];
  };

  const int NT = K >> 6;
#pragma unroll
  for (int j = 0; j < 8; ++j) STG(j, 0, 0);

  short8 af[4][2], bf[2][2];
  for (int kt = 0; kt < NT; ++kt) {
    const int cur = kt & 1, nxt = cur ^ 1;
    const bool hn = (kt + 1 < NT);
    asm volatile("s_waitcnt vmcnt(4)" ::: "memory");
    __builtin_amdgcn_s_barrier();
#pragma unroll
    for (int mi = 0; mi < 4; ++mi) { af[mi][0] = rdA(cur, mi, 0); af[mi][1] = rdA(cur, mi, 1); }
#pragma unroll
    for (int nj = 0; nj < 2; ++nj) { bf[nj][0] = rdB(cur, nj, 0); bf[nj][1] = rdB(cur, nj, 1); }
    if (hn) { STG(0, kt + 1, nxt); STG(1, kt + 1, nxt); }
    __builtin_amdgcn_s_setprio(1);
#pragma unroll
    for (int mi = 0; mi < 4; ++mi)
#pragma unroll
      for (int nj = 0; nj < 2; ++nj)
#pragma unroll
        for (int ks = 0; ks < 2; ++ks)
          acc[mi][nj] = __builtin_amdgcn_mfma_f32_16x16x32_bf16(af[mi][ks], bf[nj][ks], acc[mi][nj], 0, 0, 0);
    __builtin_amdgcn_s_setprio(0);
    if (hn) asm volatile("s_waitcnt vmcnt(4)" ::: "memory");
    else    asm volatile("s_waitcnt vmcnt(2)" ::: "memory");
    __builtin_amdgcn_s_barrier();
#pragma unroll
    for (int nj = 0; nj < 2; ++nj) { bf[nj][0] = rdB(cur, 2 + nj, 0); bf[nj][1] = rdB(cur, 2 + nj, 1); }
    if (hn) { STG(2, kt + 1, nxt); STG(3, kt + 1, nxt); }
    __builtin_amdgcn_s_setprio(1);
#pragma unroll
    for (int mi = 0; mi < 4; ++mi)
#pragma unroll
      for (int nj = 0; nj < 2; ++nj)
#pragma unroll
        for (int ks = 0; ks < 2; ++ks)
          acc[mi][2 + nj] = __builtin_amdgcn_mfma_f32_16x16x32_bf16(af[mi][ks], bf[nj][ks], acc[mi][2 + nj], 0, 0, 0);
    __builtin_amdgcn_s_setprio(0);
    if (hn) asm volatile("s_waitcnt vmcnt(4)" ::: "memory");
    else    asm volatile("s_waitcnt vmcnt(0)" ::: "memory");
    __builtin_amdgcn_s_barrier();
#pragma unroll
    for (int mi = 0; mi < 4; ++mi) { af[mi][0] = rdA(cur, 4 + mi, 0); af[mi][1] = rdA(cur, 4 + mi, 1); }
    if (hn) { STG(4, kt + 1, nxt); STG(5, kt + 1, nxt); }
    __builtin_amdgcn_s_setprio(1);
#pragma unroll
    for (int mi = 0; mi < 4; ++mi)
#pragma unroll
      for (int nj = 0; nj < 2; ++nj)
#pragma unroll
        for (int ks = 0; ks < 2; ++ks)
          acc[4 + mi][2 + nj] = __builtin_amdgcn_mfma_f32_16x16x32_bf16(af[mi][ks], bf[nj][ks], acc[4 + mi][2 + nj], 0, 0, 0);
    __builtin_amdgcn_s_setprio(0);
#pragma unroll
    for (int nj = 0; nj < 2; ++nj) { bf[nj][0] = rdB(cur, nj, 0); bf[nj][1] = rdB(cur, nj, 1); }
    if (hn) { STG(6, kt + 1, nxt); STG(7, kt + 1, nxt); }
    __builtin_amdgcn_s_setprio(1);
#pragma unroll
    for (int mi = 0; mi < 4; ++mi)
#pragma unroll
      for (int nj = 0; nj < 2; ++nj)
#pragma unroll
        for (int ks = 0; ks < 2; ++ks)
          acc[4 + mi][nj] = __builtin_amdgcn_mfma_f32_16x16x32_bf16(af[mi][ks], bf[nj][ks], acc[4 + mi][nj], 0, 0, 0);
    __builtin_amdgcn_s_setprio(0);
  }
#undef STG

  const float scale = (EPI == 3) ? 0.10412163f : 1.0f;  // log2(e)/sqrt(192)
  u16* C = (u16*)Cout;
#pragma unroll
  for (int mi = 0; mi < 8; ++mi)
#pragma unroll
    for (int nj = 0; nj < 4; ++nj) {
      u16 vals[4];
#pragma unroll
      for (int r = 0; r < 4; ++r) {
        vals[r] = f2bf(acc[mi][nj][r] * scale);
        C[(size_t)(m0 + wm * 128 + mi * 16 + lhi * 4 + r) * N + (n0 + wn * 64 + nj * 16 + llo)] =
            vals[r];
      }
      if constexpr (EPI == 2) {
        if (wn >= 2) {   // V half of the head: also scatter to Vt (B,H,128,T)
          const int n = n0 + wn * 64 + nj * 16 + llo;
          const int mb = m0 + wm * 128 + mi * 16 + lhi * 4;
          const int bb = mb >> 11, t = mb & 2047;
          const int h = n >> 8, d = (n & 255) - 128;
          *(uint2*)&Vt2[((size_t)((bb << 4) + h) * 128 + d) * (size_t)T_ + t] =
              *(const uint2*)&vals[0];
        }
      }
    }
}

// ---------------- GEMM 128x128 (r8-verified) — kept for o_w (f32 out) ----------------
template <int EPI>
__global__ __launch_bounds__(256) void gemm_bt(const u16* __restrict__ A,
                                               const u16* __restrict__ Bt,
                                               void* __restrict__ Cout,
                                               int M, int N, int K) {
  __shared__ u16 As[3][128 * 32];
  __shared__ u16 Bs[3][128 * 32];
  const int nbx = N >> 7;
  const int bx = blockIdx.x % nbx, by = blockIdx.x / nbx;
  const int m0 = by << 7, n0 = bx << 7;
  const int tid = threadIdx.x, w = tid >> 6, lane = tid & 63;
  const int wr = w >> 1, wc = w & 1;
  const int llo = lane & 15, lhi = lane >> 4;
  f32x4 acc[4][4] = {};

  const int c0 = tid, c1 = tid + 256;
  const int ar0 = c0 >> 2, s0_ = c0 & 3;
  const int ar1 = c1 >> 2, s1_ = c1 & 3;
  const u16* Asrc0 = A + (size_t)(m0 + ar0) * K + (s0_ ^ ((ar0 >> 1) & 3)) * 8;
  const u16* Asrc1 = A + (size_t)(m0 + ar1) * K + (s1_ ^ ((ar1 >> 1) & 3)) * 8;
  const u16* Bsrc0 = Bt + (size_t)(n0 + ar0) * K + (s0_ ^ ((ar0 >> 1) & 3)) * 8;
  const u16* Bsrc1 = Bt + (size_t)(n0 + ar1) * K + (s1_ ^ ((ar1 >> 1) & 3)) * 8;

  int aoff[4], boff[4];
#pragma unroll
  for (int i = 0; i < 4; ++i) {
    int rowa = wr * 64 + i * 16 + llo;
    aoff[i] = (rowa * 4 + (lhi ^ ((rowa >> 1) & 3))) * 8;
    int rowb = wc * 64 + i * 16 + llo;
    boff[i] = (rowb * 4 + (lhi ^ ((rowb >> 1) & 3))) * 8;
  }

#define STAGE_KT(kt, buf)                                   \
  do {                                                      \
    int k0_ = (kt) << 5;                                    \
    load_lds16(Asrc0 + k0_, &As[(buf)][c0 * 8]);            \
    load_lds16(Asrc1 + k0_, &As[(buf)][c1 * 8]);            \
    load_lds16(Bsrc0 + k0_, &Bs[(buf)][c0 * 8]);            \
    load_lds16(Bsrc1 + k0_, &Bs[(buf)][c1 * 8]);            \
  } while (0)

  const int NT = K >> 5;
  STAGE_KT(0, 0);
  STAGE_KT(1, 1);
  asm volatile("s_waitcnt vmcnt(4)" ::: "memory");
  __builtin_amdgcn_s_barrier();

  int cur = 0, nxt = 2;
  for (int kt = 0; kt < NT; ++kt) {
    if (kt + 2 < NT) STAGE_KT(kt + 2, nxt);
    short8 af[4], bfr[4];
#pragma unroll
    for (int i = 0; i < 4; ++i) af[i] = *(const short8*)&As[cur][aoff[i]];
#pragma unroll
    for (int j = 0; j < 4; ++j) bfr[j] = *(const short8*)&Bs[cur][boff[j]];
    __builtin_amdgcn_s_setprio(1);
#pragma unroll
    for (int i = 0; i < 4; ++i)
#pragma unroll
      for (int j = 0; j < 4; ++j)
        acc[i][j] = __builtin_amdgcn_mfma_f32_16x16x32_bf16(af[i], bfr[j], acc[i][j], 0, 0, 0);
    __builtin_amdgcn_s_setprio(0);
    if (kt + 2 < NT) asm volatile("s_waitcnt vmcnt(4)" ::: "memory");
    else             asm volatile("s_waitcnt vmcnt(0)" ::: "memory");
    __builtin_amdgcn_s_barrier();
    cur = (cur == 2) ? 0 : cur + 1;
    nxt = (nxt == 2) ? 0 : nxt + 1;
  }
#undef STAGE_KT

  if constexpr (EPI == 0) {
    float* C = (float*)Cout;
#pragma unroll
    for (int i = 0; i < 4; ++i)
#pragma unroll
      for (int j = 0; j < 4; ++j)
#pragma unroll
        for (int r = 0; r < 4; ++r)
          C[(size_t)(m0 + wr * 64 + i * 16 + lhi * 4 + r) * N + (n0 + wc * 64 + j * 16 + llo)] =
              acc[i][j][r];
  } else {
    u16* C = (u16*)Cout;
#pragma unroll
    for (int i = 0; i < 4; ++i)
#pragma unroll
      for (int j = 0; j < 4; ++j)
#pragma unroll
        for (int r = 0; r < 4; ++r)
          C[(size_t)(m0 + wr * 64 + i * 16 + lhi * 4 + r) * N + (n0 + wc * 64 + j * 16 + llo)] =
              f2bf(acc[i][j][r]);
  }
}

// ---------------- causal flash attention: 32-key tiles, 1 barrier/tile, 3 blocks/CU ----------------
// r13 retry with BOTH bugs fixed: (a) plain __launch_bounds__(256) -- min-wave
// hints forced spills in r2/r7/r13 (VGPR 84, 34MB scratch); (b) V/P swizzle
// keyed on (r>>1)&3 instead of (r&3): 64B rows alternate bank halves by row
// PARITY, so same-parity lanes need 4 distinct slots -- (r>>1)&3 cycles 0..3
// over the 8 same-parity rows of a 16-lane read -> 4 slots x 2 lanes = 2-way
// = free (m136). r13's (r&3) gave only 2 slots -> 4-way (7e6 conflicts).
// Both-sides involution (rule #21): DMA source slot sl^((rr>>1)&3), LDS dst
// lane-linear, read slot lhi^((vrow>>1)&3). K keeps r11-verified (r&7) swizzle.
// Structure: per tile {issue K/V[t+1] (5 DMA) -> 12 QK MFMA -> softmax -> 8 PV
// MFMA -> vmcnt(0)+barrier}. LDS 2x12(K)+2x8(V)+4(P) = 44KB -> 3 blocks/CU.
// Grid 512 paired blocks (qt=31-pr then pr, 66 tiles each), xcd=p&7, 4 bh/XCD.
__global__ __launch_bounds__(256) void attn_k(const u16* __restrict__ q,
                                              const u16* __restrict__ kv,
                                              const u16* __restrict__ kvraw,
                                              const u16* __restrict__ Vt,
                                              u16* __restrict__ att) {
  constexpr int KLD = 192, VLD = 32, PLD = 32;
  __shared__ u16 Ks[2][32 * KLD];   // 2 x 12 KB
  __shared__ u16 Vs[2][128 * VLD];  // 2 x 8 KB
  __shared__ u16 Ps[64 * PLD];      // 4 KB
  const int p = (int)blockIdx.x;
  const int xcd = p & 7, j = p >> 3;
  const int bh = xcd * 4 + (j & 3);   // 4 bh per XCD
  const int pr = j >> 2;              // 0..15
  const int b = bh >> 4, h = bh & 15;
  const int bT = b * T_;
  const int tid = threadIdx.x, w = tid >> 6, lane = tid & 63;
  const int llo = lane & 15, lhi = lane >> 4;
  const u16* Vb = Vt + (size_t)bh * DV_ * T_;

  // K staging: 32 rows x 24 chunks = 768 chunks, 3/thread (r11-verified swizzle)
  const u16* kbase[3]; int kstr[3];
#pragma unroll
  for (int ii = 0; ii < 3; ++ii) {
    int c = ii * 256 + tid;
    int rr = c / 24, chk = c - rr * 24;
    int sc = chk ^ (rr & 7);
    if (sc < 16) { kbase[ii] = kv + (size_t)(bT + rr) * 4096 + h * 256 + sc * 8; kstr[ii] = 4096; }
    else { kbase[ii] = kvraw + (size_t)(bT + rr) * AW_ + 2048 + h * 64 + (sc - 16) * 8; kstr[ii] = AW_; }
  }
  // V staging: 128 d-rows x 4 slots = 512 chunks, 2/thread; FIXED swizzle key
  const u16* vsrc[2];
#pragma unroll
  for (int ii = 0; ii < 2; ++ii) {
    int c = ii * 256 + tid;
    int rr = c >> 2, sl = c & 3;
    vsrc[ii] = Vb + (size_t)rr * T_ + (sl ^ ((rr >> 1) & 3)) * 8;
  }

#pragma unroll
  for (int pass = 0; pass < 2; ++pass) {
    const int qt = pass == 0 ? 31 - pr : pr;
    const int q0 = qt * 64;
    const int rbase = q0 + w * 16;
    short8 qf[6];
#pragma unroll
    for (int kk = 0; kk < 6; ++kk)
      qf[kk] = *(const short8*)&q[(size_t)(bT + rbase + llo) * AW_ + h * DQK_ + kk * 32 + lhi * 8];
    f32x4 oacc[8] = {};
    float m_r[4], l_r[4];
#pragma unroll
    for (int r = 0; r < 4; ++r) { m_r[r] = -1e30f; l_r[r] = 0.f; }

    // prologue: stage K[0], V[0] into buffer 0
#pragma unroll
    for (int ii = 0; ii < 3; ++ii)
      load_lds16(kbase[ii], &Ks[0][(ii * 256 + tid) * 8]);
#pragma unroll
    for (int ii = 0; ii < 2; ++ii)
      load_lds16(vsrc[ii], &Vs[0][(ii * 256 + tid) * 8]);
    asm volatile("s_waitcnt vmcnt(0)" ::: "memory");
    __builtin_amdgcn_s_barrier();
    __builtin_amdgcn_sched_barrier(0);

    const int nkt = 2 * qt + 2;   // 32-key tiles
    int cur = 0;
    for (int kt = 0; kt < nkt; ++kt) {
      const int k0 = kt * 32;
      // issue next tile's K/V into the other buffers
      if (kt + 1 < nkt) {
        u16* kd = Ks[cur ^ 1];
        u16* vd = Vs[cur ^ 1];
#pragma unroll
        for (int ii = 0; ii < 3; ++ii)
          load_lds16(kbase[ii] + (size_t)(k0 + 32) * kstr[ii], &kd[(ii * 256 + tid) * 8]);
#pragma unroll
        for (int ii = 0; ii < 2; ++ii)
          load_lds16(vsrc[ii] + k0 + 32, &vd[(ii * 256 + tid) * 8]);
      }
      // S = Q K^T from Ks[cur]  (2 col-frags of 16 keys)
      const u16* kbuf = Ks[cur];
      f32x4 s[2] = {};
      __builtin_amdgcn_s_setprio(1);
#pragma unroll
      for (int kk = 0; kk < 6; ++kk) {
        const int col = kk * 32 + lhi * 8;
        short8 kf[2];
#pragma unroll
        for (int j2 = 0; j2 < 2; ++j2) {
          const int row = j2 * 16 + llo;
          kf[j2] = *(const short8*)&kbuf[row * KLD + (col ^ ((row & 7) << 3))];
        }
#pragma unroll
        for (int j2 = 0; j2 < 2; ++j2)
          s[j2] = __builtin_amdgcn_mfma_f32_16x16x32_bf16(qf[kk], kf[j2], s[j2], 0, 0, 0);
      }
      __builtin_amdgcn_s_setprio(0);
      // online softmax (exp2 domain; Q pre-scaled by log2e/sqrt(192))
      const bool needMask = (k0 + 31 > rbase);
#pragma unroll
      for (int r = 0; r < 4; ++r) {
        const int qrow = rbase + lhi * 4 + r;
        float sv[2];
#pragma unroll
        for (int j2 = 0; j2 < 2; ++j2) {
          float x = s[j2][r];
          if (needMask) { int kcol = k0 + j2 * 16 + llo; x = (kcol <= qrow) ? x : -1e30f; }
          sv[j2] = x;
        }
        float mx2 = fmaxf(sv[0], sv[1]);
        if (!__all(mx2 - m_r[r] <= 8.f)) {   // lazy row-max (T13)
          float mx = mx2;
#pragma unroll
          for (int mk = 1; mk < 16; mk <<= 1) mx = fmaxf(mx, __shfl_xor(mx, mk));
          float mnew = fmaxf(m_r[r], mx);
          float alpha = exp2f(m_r[r] - mnew);
          m_r[r] = mnew;
          l_r[r] *= alpha;
#pragma unroll
          for (int jo = 0; jo < 8; ++jo) oacc[jo][r] *= alpha;
        }
        const int prow = w * 16 + lhi * 4 + r;
        float rs = 0.f;
#pragma unroll
        for (int j2 = 0; j2 < 2; ++j2) {
          float pv = exp2f(sv[j2] - m_r[r]);   // bounded by 2^8
          rs += pv;
          int pcol = j2 * 16 + llo;
          int slot = pcol >> 3;
          Ps[prow * PLD + ((slot ^ ((prow >> 1) & 3)) << 3) + (pcol & 7)] = f2bf(pv);
        }
        l_r[r] += rs;   // per-lane partial; cross-lane reduce in epilogue
      }
      // PV from Vs[cur], Ps (wave-private rows; same-wave lgkmcnt orders RAW)
      __builtin_amdgcn_s_setprio(1);
      {
        const int prow = w * 16 + llo;
        short8 pf = *(const short8*)&Ps[prow * PLD + ((lhi ^ ((prow >> 1) & 3)) << 3)];
#pragma unroll
        for (int jo = 0; jo < 8; ++jo) {
          const int vrow = jo * 16 + llo;
          short8 vf = *(const short8*)&Vs[cur][vrow * VLD + ((lhi ^ ((vrow >> 1) & 3)) << 3)];
          oacc[jo] = __builtin_amdgcn_mfma_f32_16x16x32_bf16(pf, vf, oacc[jo], 0, 0, 0);
        }
      }
      __builtin_amdgcn_s_setprio(0);
      // single drain+barrier per tile: next K/V landed (all waves), buffers free
      asm volatile("s_waitcnt vmcnt(0)" ::: "memory");
      __builtin_amdgcn_s_barrier();
      __builtin_amdgcn_sched_barrier(0);
      cur ^= 1;
    }
    // epilogue: reduce l partials across 16-lane group, store
#pragma unroll
    for (int r = 0; r < 4; ++r) {
      float lr = l_r[r];
#pragma unroll
      for (int mk = 1; mk < 16; mk <<= 1) lr += __shfl_xor(lr, mk);
      const int qrow = rbase + lhi * 4 + r;
      const float linv = 1.f / lr;
#pragma unroll
      for (int jo = 0; jo < 8; ++jo)
        att[((size_t)bT + qrow) * (H_ * DV_) + h * DV_ + jo * 16 + llo] =
            f2bf(oacc[jo][r] * linv);
    }
  }
}

// ---------------- launch ----------------
extern "C" void kernel_launch(void* const* d_in, const int* in_sizes, int n_in,
                              void* d_out, int out_size, void* d_ws, size_t ws_size,
                              hipStream_t stream) {
  const float* hs      = (const float*)d_in[0];
  const float* q_a_w   = (const float*)d_in[1];
  const float* q_a_ln  = (const float*)d_in[2];
  const float* q_b_w   = (const float*)d_in[3];
  const float* kv_a_w  = (const float*)d_in[4];
  const float* kv_a_ln = (const float*)d_in[5];
  const float* kv_b_w  = (const float*)d_in[6];
  const float* o_w     = (const float*)d_in[7];
  float* out = (float*)d_out;
  char* ws = (char*)d_ws;

  u16* hid  = (u16*)(ws + 0);          // 16.78 MB  (B*T, 2048) bf16
  u16* wt   = (u16*)(ws + 16777216);   // 12.58 MB  transposed weight (reused)
  u16* qa   = (u16*)(ws + 29360128);   // 25.17 MB  fused a-out: [q_a 1536 | kv_raw 1536]
  u16* qan  = (u16*)(ws + 54525952);   // 12.58 MB  q_a normed (stride 1536)
  u16* qout = (u16*)(ws + 67108864);   // 25.17 MB  q (B*T, 16*192), pre-scaled
  u16* att  = (u16*)(ws + 92274688);   // 16.78 MB  attn out (B*T, 2048)
  u16* kv   = (u16*)(ws + 109051904);  // 33.55 MB  kv_b out (k_nope|v per head)
  u16* Vt   = (u16*)(ws + 142606336);  // 16.78 MB  (B,H,128,T)
  u16* qan2 = (u16*)(ws + 159383552);  //  4.19 MB  kv latent normed (stride 512)

  cast_f32_bf16<<<4096, 256, 0, stream>>>(hs, hid);

  // fused a-proj: [q_a | kv_raw] = hid @ [q_a_w | kv_a_w]   (256^2 pipeline)
  transpose_cast_k<<<dim3(1536 / 32, 2048 / 32), 256, 0, stream>>>(q_a_w, wt, 2048, 1536);
  transpose_cast_k<<<dim3(1536 / 32, 2048 / 32), 256, 0, stream>>>(kv_a_w, wt + (size_t)1536 * 2048, 2048, 1536);
  gemm256<1><<<(3072 / 256) * (4096 / 256), 512, 0, stream>>>(hid, wt, qa, nullptr, 4096, 3072, 2048);

  // both RMSNorms in one launch: q_a -> qan, kv latent -> qan2
  rmsnorm_dual<<<4096, 256, 0, stream>>>(qa, q_a_ln, qan, kv_a_ln, qan2);

  // q = qan @ q_b_w  (bf16, pre-scaled by log2e/sqrt(192))
  transpose_cast_k<<<dim3(3072 / 32, 1536 / 32), 256, 0, stream>>>(q_b_w, wt, 1536, 3072);
  gemm256<3><<<(3072 / 256) * (4096 / 256), 512, 0, stream>>>(qan, wt, qout, nullptr, 4096, 3072, 1536);

  // kv = qan2 @ kv_b_w  -> kv row-major + Vt scatter fused
  transpose_cast_k<<<dim3(4096 / 32, 512 / 32), 256, 0, stream>>>(kv_b_w, wt, 512, 4096);
  gemm256<2><<<(4096 / 256) * (4096 / 256), 512, 0, stream>>>(qan2, wt, kv, Vt, 4096, 4096, 512);

  // attention -> att  (512 paired blocks, 32-key tiles, 3 blocks/CU)
  attn_k<<<512, 256, 0, stream>>>(qout, kv, qa, Vt, att);

  // out = att @ o_w   (r8-verified 128^2 kernel, f32 out)
  transpose_cast_k<<<dim3(2048 / 32, 2048 / 32), 256, 0, stream>>>(o_w, wt, 2048, 2048);
  gemm_bt<0><<<(2048 / 128) * (4096 / 128), 256, 0, stream>>>(att, wt, out, 4096, 2048, 2048);
}

// Round 17
// 312.434 us; speedup vs baseline: 1.0731x; 1.0731x over previous
//
#include <hip/hip_runtime.h>
#include <cstdint>
#include <cstddef>

typedef unsigned short u16;
typedef short short8 __attribute__((ext_vector_type(8)));
typedef float f32x4 __attribute__((ext_vector_type(4)));

#define B_   2
#define T_   2048
#define H_   16
#define HID_ 2048
#define DQK_ 192
#define DV_  128
#define AW_  3072   // fused a-proj output width (q_a 1536 | kv_raw 1536)

__device__ __forceinline__ float bf2f(u16 u) {
  unsigned int v = ((unsigned int)u) << 16;
  return __builtin_bit_cast(float, v);
}
__device__ __forceinline__ u16 f2bf(float f) {
  unsigned int u = __builtin_bit_cast(unsigned int, f);
  u += 0x7fff + ((u >> 16) & 1);   // round-to-nearest-even
  return (u16)(u >> 16);
}
__device__ __forceinline__ void load_lds16(const void* g, void* l) {
  __builtin_amdgcn_global_load_lds((const __attribute__((address_space(1))) void*)g,
                                   (__attribute__((address_space(3))) void*)l, 16, 0, 0);
}

// ---------------- cast f32 -> bf16 (8 elems/thread) ----------------
__global__ __launch_bounds__(256) void cast_f32_bf16(const float* __restrict__ x,
                                                     u16* __restrict__ y) {
  size_t i = ((size_t)blockIdx.x * 256 + threadIdx.x) * 8;
  float4 a = *(const float4*)&x[i];
  float4 b = *(const float4*)&x[i + 4];
  u16 r[8];
  r[0] = f2bf(a.x); r[1] = f2bf(a.y); r[2] = f2bf(a.z); r[3] = f2bf(a.w);
  r[4] = f2bf(b.x); r[5] = f2bf(b.y); r[6] = f2bf(b.z); r[7] = f2bf(b.w);
  *(uint4*)&y[i] = *(const uint4*)&r[0];
}

// ---------------- W (K x N) f32  ->  Wt (N x K) bf16 ----------------
__global__ __launch_bounds__(256) void transpose_cast_k(const float* __restrict__ W,
                                                        u16* __restrict__ Wt,
                                                        int K, int N) {
  __shared__ u16 tile[32][33];
  int n0 = blockIdx.x * 32, k0 = blockIdx.y * 32;
  int tx = threadIdx.x & 31, ty = threadIdx.x >> 5;
#pragma unroll
  for (int i = 0; i < 32; i += 8)
    tile[ty + i][tx] = f2bf(W[(size_t)(k0 + ty + i) * N + n0 + tx]);
  __syncthreads();
#pragma unroll
  for (int i = 0; i < 32; i += 8)
    Wt[(size_t)(n0 + ty + i) * K + k0 + tx] = tile[tx][ty + i];
}

// ---------------- dual RMSNorm: q_a (L=1536) -> out1, kv latent (L=512) -> out2 ----------------
__global__ __launch_bounds__(256) void rmsnorm_dual(const u16* __restrict__ qa,
                                                    const float* __restrict__ w1,
                                                    u16* __restrict__ out1,
                                                    const float* __restrict__ w2,
                                                    u16* __restrict__ out2) {
  __shared__ float red[4];
  const int row = blockIdx.x, tid = threadIdx.x;
  {
    const u16* x = qa + (size_t)row * AW_;
    float ss = 0.f;
    for (int i = tid * 8; i < 1536; i += 2048) {
      uint4 v = *(const uint4*)&x[i];
      const u16* p = (const u16*)&v;
#pragma unroll
      for (int e = 0; e < 8; ++e) { float f = bf2f(p[e]); ss += f * f; }
    }
#pragma unroll
    for (int m = 32; m >= 1; m >>= 1) ss += __shfl_xor(ss, m);
    if ((tid & 63) == 0) red[tid >> 6] = ss;
    __syncthreads();
    ss = red[0] + red[1] + red[2] + red[3];
    float inv = rsqrtf(ss / 1536.f + 1e-6f);
    u16* o = out1 + (size_t)row * 1536;
    for (int i = tid * 8; i < 1536; i += 2048) {
      uint4 v = *(const uint4*)&x[i];
      const u16* p = (const u16*)&v;
      u16 r8[8];
#pragma unroll
      for (int e = 0; e < 8; ++e) r8[e] = f2bf(bf2f(p[e]) * inv * w1[i + e]);
      *(uint4*)&o[i] = *(const uint4*)&r8[0];
    }
  }
  __syncthreads();
  {
    const u16* x = qa + (size_t)row * AW_ + 1536;
    float ss = 0.f;
    for (int i = tid * 8; i < 512; i += 2048) {
      uint4 v = *(const uint4*)&x[i];
      const u16* p = (const u16*)&v;
#pragma unroll
      for (int e = 0; e < 8; ++e) { float f = bf2f(p[e]); ss += f * f; }
    }
#pragma unroll
    for (int m = 32; m >= 1; m >>= 1) ss += __shfl_xor(ss, m);
    if ((tid & 63) == 0) red[tid >> 6] = ss;
    __syncthreads();
    ss = red[0] + red[1] + red[2] + red[3];
    float inv = rsqrtf(ss / 512.f + 1e-6f);
    u16* o = out2 + (size_t)row * 512;
    for (int i = tid * 8; i < 512; i += 2048) {
      uint4 v = *(const uint4*)&x[i];
      const u16* p = (const u16*)&v;
      u16 r8[8];
#pragma unroll
      for (int e = 0; e < 8; ++e) r8[e] = f2bf(bf2f(p[e]) * inv * w2[i + e]);
      *(uint4*)&o[i] = *(const uint4*)&r8[0];
    }
  }
}

// ---------------- GEMM 256x256 (4-phase), BK=64, 512 thr / 8 waves ----------------
// Verified r14/r15. EPI: 1 = bf16; 3 = bf16 * softmax scale; 2 = bf16 + Vt scatter.
template <int EPI>
__global__ __launch_bounds__(512) void gemm256(const u16* __restrict__ A,
                                               const u16* __restrict__ Bt,
                                               void* __restrict__ Cout,
                                               u16* __restrict__ Vt2,
                                               int M, int N, int K) {
  __shared__ u16 As[2][256 * 64];   // 64 KB
  __shared__ u16 Bs[2][256 * 64];   // 64 KB
  const int nbx = N >> 8;
  const int bx = blockIdx.x % nbx, by = blockIdx.x / nbx;
  const int m0 = by << 8, n0 = bx << 8;
  const int tid = threadIdx.x, w = tid >> 6, lane = tid & 63;
  const int wm = w >> 2, wn = w & 3;
  const int llo = lane & 15, lhi = lane >> 4;
  f32x4 acc[8][4] = {};

  const u16* srcp[8];
  int dsto[8];
#pragma unroll
  for (int jl = 0; jl < 2; ++jl) {
    int c = jl * 512 + tid;
    int i = c >> 3, sl = c & 7;
    { int r = ((i >> 6) << 7) + (i & 63);
      srcp[jl] = A + (size_t)(m0 + r) * K + ((sl ^ (r & 7)) << 3);
      dsto[jl] = (r * 8 + sl) * 8; }
    { int r = ((i >> 5) << 6) + (i & 31);
      srcp[2 + jl] = Bt + (size_t)(n0 + r) * K + ((sl ^ (r & 7)) << 3);
      dsto[2 + jl] = (r * 8 + sl) * 8; }
    { int r = ((i >> 5) << 6) + 32 + (i & 31);
      srcp[4 + jl] = Bt + (size_t)(n0 + r) * K + ((sl ^ (r & 7)) << 3);
      dsto[4 + jl] = (r * 8 + sl) * 8; }
    { int r = ((i >> 6) << 7) + 64 + (i & 63);
      srcp[6 + jl] = A + (size_t)(m0 + r) * K + ((sl ^ (r & 7)) << 3);
      dsto[6 + jl] = (r * 8 + sl) * 8; }
  }
#define STG(j, kt, buf)                                                        \
  load_lds16(srcp[j] + (size_t)(kt) * 64,                                      \
             ((j) < 2 || (j) >= 6) ? &As[(buf)][dsto[j]] : &Bs[(buf)][dsto[j]])

  auto rdA = [&](int buf, int mi, int ks) {
    int r = wm * 128 + mi * 16 + llo;
    return *(const short8*)&As[buf][r * 64 + (((ks * 4 + lhi) ^ (r & 7)) << 3)];
  };
  auto rdB = [&](int buf, int nj, int ks) {
    int r = wn * 64 + nj * 16 + llo;
    return *(const short8*)&Bs[buf][r * 64 + (((ks * 4 + lhi) ^ (r & 7)) << 3)];
  };

  const int NT = K >> 6;
#pragma unroll
  for (int j = 0; j < 8; ++j) STG(j, 0, 0);

  short8 af[4][2], bf[2][2];
  for (int kt = 0; kt < NT; ++kt) {
    const int cur = kt & 1, nxt = cur ^ 1;
    const bool hn = (kt + 1 < NT);
    asm volatile("s_waitcnt vmcnt(4)" ::: "memory");
    __builtin_amdgcn_s_barrier();
#pragma unroll
    for (int mi = 0; mi < 4; ++mi) { af[mi][0] = rdA(cur, mi, 0); af[mi][1] = rdA(cur, mi, 1); }
#pragma unroll
    for (int nj = 0; nj < 2; ++nj) { bf[nj][0] = rdB(cur, nj, 0); bf[nj][1] = rdB(cur, nj, 1); }
    if (hn) { STG(0, kt + 1, nxt); STG(1, kt + 1, nxt); }
    __builtin_amdgcn_s_setprio(1);
#pragma unroll
    for (int mi = 0; mi < 4; ++mi)
#pragma unroll
      for (int nj = 0; nj < 2; ++nj)
#pragma unroll
        for (int ks = 0; ks < 2; ++ks)
          acc[mi][nj] = __builtin_amdgcn_mfma_f32_16x16x32_bf16(af[mi][ks], bf[nj][ks], acc[mi][nj], 0, 0, 0);
    __builtin_amdgcn_s_setprio(0);
    if (hn) asm volatile("s_waitcnt vmcnt(4)" ::: "memory");
    else    asm volatile("s_waitcnt vmcnt(2)" ::: "memory");
    __builtin_amdgcn_s_barrier();
#pragma unroll
    for (int nj = 0; nj < 2; ++nj) { bf[nj][0] = rdB(cur, 2 + nj, 0); bf[nj][1] = rdB(cur, 2 + nj, 1); }
    if (hn) { STG(2, kt + 1, nxt); STG(3, kt + 1, nxt); }
    __builtin_amdgcn_s_setprio(1);
#pragma unroll
    for (int mi = 0; mi < 4; ++mi)
#pragma unroll
      for (int nj = 0; nj < 2; ++nj)
#pragma unroll
        for (int ks = 0; ks < 2; ++ks)
          acc[mi][2 + nj] = __builtin_amdgcn_mfma_f32_16x16x32_bf16(af[mi][ks], bf[nj][ks], acc[mi][2 + nj], 0, 0, 0);
    __builtin_amdgcn_s_setprio(0);
    if (hn) asm volatile("s_waitcnt vmcnt(4)" ::: "memory");
    else    asm volatile("s_waitcnt vmcnt(0)" ::: "memory");
    __builtin_amdgcn_s_barrier();
#pragma unroll
    for (int mi = 0; mi < 4; ++mi) { af[mi][0] = rdA(cur, 4 + mi, 0); af[mi][1] = rdA(cur, 4 + mi, 1); }
    if (hn) { STG(4, kt + 1, nxt); STG(5, kt + 1, nxt); }
    __builtin_amdgcn_s_setprio(1);
#pragma unroll
    for (int mi = 0; mi < 4; ++mi)
#pragma unroll
      for (int nj = 0; nj < 2; ++nj)
#pragma unroll
        for (int ks = 0; ks < 2; ++ks)
          acc[4 + mi][2 + nj] = __builtin_amdgcn_mfma_f32_16x16x32_bf16(af[mi][ks], bf[nj][ks], acc[4 + mi][2 + nj], 0, 0, 0);
    __builtin_amdgcn_s_setprio(0);
#pragma unroll
    for (int nj = 0; nj < 2; ++nj) { bf[nj][0] = rdB(cur, nj, 0); bf[nj][1] = rdB(cur, nj, 1); }
    if (hn) { STG(6, kt + 1, nxt); STG(7, kt + 1, nxt); }
    __builtin_amdgcn_s_setprio(1);
#pragma unroll
    for (int mi = 0; mi < 4; ++mi)
#pragma unroll
      for (int nj = 0; nj < 2; ++nj)
#pragma unroll
        for (int ks = 0; ks < 2; ++ks)
          acc[4 + mi][nj] = __builtin_amdgcn_mfma_f32_16x16x32_bf16(af[mi][ks], bf[nj][ks], acc[4 + mi][nj], 0, 0, 0);
    __builtin_amdgcn_s_setprio(0);
  }
#undef STG

  const float scale = (EPI == 3) ? 0.10412163f : 1.0f;  // log2(e)/sqrt(192)
  u16* C = (u16*)Cout;
#pragma unroll
  for (int mi = 0; mi < 8; ++mi)
#pragma unroll
    for (int nj = 0; nj < 4; ++nj) {
      u16 vals[4];
#pragma unroll
      for (int r = 0; r < 4; ++r) {
        vals[r] = f2bf(acc[mi][nj][r] * scale);
        C[(size_t)(m0 + wm * 128 + mi * 16 + lhi * 4 + r) * N + (n0 + wn * 64 + nj * 16 + llo)] =
            vals[r];
      }
      if constexpr (EPI == 2) {
        if (wn >= 2) {   // V half of the head: also scatter to Vt (B,H,128,T)
          const int n = n0 + wn * 64 + nj * 16 + llo;
          const int mb = m0 + wm * 128 + mi * 16 + lhi * 4;
          const int bb = mb >> 11, t = mb & 2047;
          const int h = n >> 8, d = (n & 255) - 128;
          *(uint2*)&Vt2[((size_t)((bb << 4) + h) * 128 + d) * (size_t)T_ + t] =
              *(const uint2*)&vals[0];
        }
      }
    }
}

// ---------------- GEMM 128x128 (r8-verified) — kept for o_w (f32 out) ----------------
template <int EPI>
__global__ __launch_bounds__(256) void gemm_bt(const u16* __restrict__ A,
                                               const u16* __restrict__ Bt,
                                               void* __restrict__ Cout,
                                               int M, int N, int K) {
  __shared__ u16 As[3][128 * 32];
  __shared__ u16 Bs[3][128 * 32];
  const int nbx = N >> 7;
  const int bx = blockIdx.x % nbx, by = blockIdx.x / nbx;
  const int m0 = by << 7, n0 = bx << 7;
  const int tid = threadIdx.x, w = tid >> 6, lane = tid & 63;
  const int wr = w >> 1, wc = w & 1;
  const int llo = lane & 15, lhi = lane >> 4;
  f32x4 acc[4][4] = {};

  const int c0 = tid, c1 = tid + 256;
  const int ar0 = c0 >> 2, s0_ = c0 & 3;
  const int ar1 = c1 >> 2, s1_ = c1 & 3;
  const u16* Asrc0 = A + (size_t)(m0 + ar0) * K + (s0_ ^ ((ar0 >> 1) & 3)) * 8;
  const u16* Asrc1 = A + (size_t)(m0 + ar1) * K + (s1_ ^ ((ar1 >> 1) & 3)) * 8;
  const u16* Bsrc0 = Bt + (size_t)(n0 + ar0) * K + (s0_ ^ ((ar0 >> 1) & 3)) * 8;
  const u16* Bsrc1 = Bt + (size_t)(n0 + ar1) * K + (s1_ ^ ((ar1 >> 1) & 3)) * 8;

  int aoff[4], boff[4];
#pragma unroll
  for (int i = 0; i < 4; ++i) {
    int rowa = wr * 64 + i * 16 + llo;
    aoff[i] = (rowa * 4 + (lhi ^ ((rowa >> 1) & 3))) * 8;
    int rowb = wc * 64 + i * 16 + llo;
    boff[i] = (rowb * 4 + (lhi ^ ((rowb >> 1) & 3))) * 8;
  }

#define STAGE_KT(kt, buf)                                   \
  do {                                                      \
    int k0_ = (kt) << 5;                                    \
    load_lds16(Asrc0 + k0_, &As[(buf)][c0 * 8]);            \
    load_lds16(Asrc1 + k0_, &As[(buf)][c1 * 8]);            \
    load_lds16(Bsrc0 + k0_, &Bs[(buf)][c0 * 8]);            \
    load_lds16(Bsrc1 + k0_, &Bs[(buf)][c1 * 8]);            \
  } while (0)

  const int NT = K >> 5;
  STAGE_KT(0, 0);
  STAGE_KT(1, 1);
  asm volatile("s_waitcnt vmcnt(4)" ::: "memory");
  __builtin_amdgcn_s_barrier();

  int cur = 0, nxt = 2;
  for (int kt = 0; kt < NT; ++kt) {
    if (kt + 2 < NT) STAGE_KT(kt + 2, nxt);
    short8 af[4], bfr[4];
#pragma unroll
    for (int i = 0; i < 4; ++i) af[i] = *(const short8*)&As[cur][aoff[i]];
#pragma unroll
    for (int j = 0; j < 4; ++j) bfr[j] = *(const short8*)&Bs[cur][boff[j]];
    __builtin_amdgcn_s_setprio(1);
#pragma unroll
    for (int i = 0; i < 4; ++i)
#pragma unroll
      for (int j = 0; j < 4; ++j)
        acc[i][j] = __builtin_amdgcn_mfma_f32_16x16x32_bf16(af[i], bfr[j], acc[i][j], 0, 0, 0);
    __builtin_amdgcn_s_setprio(0);
    if (kt + 2 < NT) asm volatile("s_waitcnt vmcnt(4)" ::: "memory");
    else             asm volatile("s_waitcnt vmcnt(0)" ::: "memory");
    __builtin_amdgcn_s_barrier();
    cur = (cur == 2) ? 0 : cur + 1;
    nxt = (nxt == 2) ? 0 : nxt + 1;
  }
#undef STAGE_KT

  if constexpr (EPI == 0) {
    float* C = (float*)Cout;
#pragma unroll
    for (int i = 0; i < 4; ++i)
#pragma unroll
      for (int j = 0; j < 4; ++j)
#pragma unroll
        for (int r = 0; r < 4; ++r)
          C[(size_t)(m0 + wr * 64 + i * 16 + lhi * 4 + r) * N + (n0 + wc * 64 + j * 16 + llo)] =
              acc[i][j][r];
  } else {
    u16* C = (u16*)Cout;
#pragma unroll
    for (int i = 0; i < 4; ++i)
#pragma unroll
      for (int j = 0; j < 4; ++j)
#pragma unroll
        for (int r = 0; r < 4; ++r)
          C[(size_t)(m0 + wr * 64 + i * 16 + lhi * 4 + r) * N + (n0 + wc * 64 + j * 16 + llo)] =
              f2bf(acc[i][j][r]);
  }
}

// ---------------- causal flash attention (r14-verified: 100us) ----------------
// block 256 (4 waves x 16 q-rows); k-tile 64; TWO passes (qt=31-pr, qt=pr) = 33
// k-tiles/block. xcd=p&7, bh=xcd*4+(j&3) -> 4 bh/XCD (FETCH 42MB, r11-verified).
// global_load_lds staging (indexed addressing -- r15's running ptrs were
// neutral-negative), K dbuf, counted vmcnt, source-side XOR (rule #21), exp2
// softmax, lazy row-max (T13), deferred l-reduce. LDS 72KB -> 2 blocks/CU.
// NOTE: 4 structural variants (zero-staging r5, 512-thr r7, 128-row r9,
// 32-key r13/r16) all lost to this 64-key shape -- do not re-scale the tile.
__global__ __launch_bounds__(256, 2) void attn_k(const u16* __restrict__ q,
                                                 const u16* __restrict__ kv,
                                                 const u16* __restrict__ kvraw,
                                                 const u16* __restrict__ Vt,
                                                 u16* __restrict__ att) {
  constexpr int KLD = 192, VLD = 64, PLD = 64;
  __shared__ u16 Ks[2][64 * KLD];
  __shared__ u16 Vs[128 * VLD];
  __shared__ u16 Ps[64 * PLD];
  const int p = (int)blockIdx.x;
  const int xcd = p & 7, j = p >> 3;
  const int bh = xcd * 4 + (j & 3);   // 4 bh per XCD
  const int pr = j >> 2;              // 0..15
  const int b = bh >> 4, h = bh & 15;
  const int bT = b * T_;
  const int tid = threadIdx.x, w = tid >> 6, lane = tid & 63;
  const int llo = lane & 15, lhi = lane >> 4;
  const u16* Vb = Vt + (size_t)bh * DV_ * T_;

  const u16* kbase[6]; int kstr[6];
#pragma unroll
  for (int ii = 0; ii < 6; ++ii) {
    int c = ii * 256 + tid;
    int rr = c / 24, chk = c - rr * 24;
    int sc = chk ^ (rr & 7);
    if (sc < 16) { kbase[ii] = kv + (size_t)(bT + rr) * 4096 + h * 256 + sc * 8; kstr[ii] = 4096; }
    else { kbase[ii] = kvraw + (size_t)(bT + rr) * AW_ + 2048 + h * 64 + (sc - 16) * 8; kstr[ii] = AW_; }
  }
  int voff[4];
#pragma unroll
  for (int ii = 0; ii < 4; ++ii) {
    int c = ii * 256 + tid;
    int rr = c >> 3, chk = c & 7;
    voff[ii] = rr * T_ + (chk ^ (rr & 7)) * 8;
  }

#pragma unroll
  for (int pass = 0; pass < 2; ++pass) {
    const int qt = pass == 0 ? 31 - pr : pr;
    const int q0 = qt * 64;
    const int rbase = q0 + w * 16;
    short8 qf[6];
#pragma unroll
    for (int kk = 0; kk < 6; ++kk)
      qf[kk] = *(const short8*)&q[(size_t)(bT + rbase + llo) * AW_ + h * DQK_ + kk * 32 + lhi * 8];
    f32x4 oacc[8] = {};
    float m_r[4], l_r[4];
#pragma unroll
    for (int r = 0; r < 4; ++r) { m_r[r] = -1e30f; l_r[r] = 0.f; }

#pragma unroll
    for (int ii = 0; ii < 6; ++ii)
      load_lds16(kbase[ii], &Ks[0][(ii * 256 + tid) * 8]);
    asm volatile("s_waitcnt vmcnt(0)" ::: "memory");
    __builtin_amdgcn_s_barrier();
    __builtin_amdgcn_sched_barrier(0);

    const int nkt = qt + 1;
    int cur = 0;
    for (int kt = 0; kt < nkt; ++kt) {
      const int k0 = kt * 64;
      const bool hasNext = (kt + 1 < nkt);
#pragma unroll
      for (int ii = 0; ii < 4; ++ii)
        load_lds16(Vb + k0 + voff[ii], &Vs[(ii * 256 + tid) * 8]);
      if (hasNext) {
        u16* kd = Ks[cur ^ 1];
#pragma unroll
        for (int ii = 0; ii < 6; ++ii)
          load_lds16(kbase[ii] + (size_t)(k0 + 64) * kstr[ii], &kd[(ii * 256 + tid) * 8]);
      }
      const u16* kbuf = Ks[cur];
      f32x4 s[4] = {};
      __builtin_amdgcn_s_setprio(1);
#pragma unroll
      for (int kk = 0; kk < 6; ++kk) {
        const int col = kk * 32 + lhi * 8;
        short8 kf[4];
#pragma unroll
        for (int j2 = 0; j2 < 4; ++j2) {
          const int row = j2 * 16 + llo;
          kf[j2] = *(const short8*)&kbuf[row * KLD + (col ^ ((row & 7) << 3))];
        }
#pragma unroll
        for (int j2 = 0; j2 < 4; ++j2)
          s[j2] = __builtin_amdgcn_mfma_f32_16x16x32_bf16(qf[kk], kf[j2], s[j2], 0, 0, 0);
      }
      __builtin_amdgcn_s_setprio(0);
      const bool needMask = (k0 + 63 > rbase);
#pragma unroll
      for (int r = 0; r < 4; ++r) {
        const int qrow = rbase + lhi * 4 + r;
        float sv[4];
#pragma unroll
        for (int j2 = 0; j2 < 4; ++j2) {
          float x = s[j2][r];
          if (needMask) { int kcol = k0 + j2 * 16 + llo; x = (kcol <= qrow) ? x : -1e30f; }
          sv[j2] = x;
        }
        float mx4 = fmaxf(fmaxf(sv[0], sv[1]), fmaxf(sv[2], sv[3]));
        if (!__all(mx4 - m_r[r] <= 8.f)) {
          float mx = mx4;
#pragma unroll
          for (int mk = 1; mk < 16; mk <<= 1) mx = fmaxf(mx, __shfl_xor(mx, mk));
          float mnew = fmaxf(m_r[r], mx);
          float alpha = exp2f(m_r[r] - mnew);
          m_r[r] = mnew;
          l_r[r] *= alpha;
#pragma unroll
          for (int jo = 0; jo < 8; ++jo) oacc[jo][r] *= alpha;
        }
        float rs = 0.f;
        const int prow = w * 16 + lhi * 4 + r;
#pragma unroll
        for (int j2 = 0; j2 < 4; ++j2) {
          float p2 = exp2f(sv[j2] - m_r[r]);
          rs += p2;
          int pcol = j2 * 16 + llo;
          Ps[prow * PLD + (pcol ^ ((prow & 7) << 3))] = f2bf(p2);
        }
        l_r[r] += rs;
      }
      if (hasNext) asm volatile("s_waitcnt vmcnt(6)" ::: "memory");
      else         asm volatile("s_waitcnt vmcnt(0)" ::: "memory");
      __builtin_amdgcn_s_barrier();
      __builtin_amdgcn_sched_barrier(0);
      __builtin_amdgcn_s_setprio(1);
#pragma unroll
      for (int kk2 = 0; kk2 < 2; ++kk2) {
        const int prow = w * 16 + llo;
        const int pcol = kk2 * 32 + lhi * 8;
        short8 pf = *(const short8*)&Ps[prow * PLD + (pcol ^ ((prow & 7) << 3))];
#pragma unroll
        for (int jo = 0; jo < 8; ++jo) {
          const int vrow = jo * 16 + llo;
          short8 vf = *(const short8*)&Vs[vrow * VLD + (pcol ^ ((vrow & 7) << 3))];
          oacc[jo] = __builtin_amdgcn_mfma_f32_16x16x32_bf16(pf, vf, oacc[jo], 0, 0, 0);
        }
      }
      __builtin_amdgcn_s_setprio(0);
      asm volatile("s_waitcnt vmcnt(0)" ::: "memory");
      __builtin_amdgcn_s_barrier();
      __builtin_amdgcn_sched_barrier(0);
      cur ^= 1;
    }
#pragma unroll
    for (int r = 0; r < 4; ++r) {
      float lr = l_r[r];
#pragma unroll
      for (int mk = 1; mk < 16; mk <<= 1) lr += __shfl_xor(lr, mk);
      const int qrow = rbase + lhi * 4 + r;
      const float linv = 1.f / lr;
#pragma unroll
      for (int jo = 0; jo < 8; ++jo)
        att[((size_t)bT + qrow) * (H_ * DV_) + h * DV_ + jo * 16 + llo] =
            f2bf(oacc[jo][r] * linv);
    }
  }
}

// ---------------- launch ----------------
extern "C" void kernel_launch(void* const* d_in, const int* in_sizes, int n_in,
                              void* d_out, int out_size, void* d_ws, size_t ws_size,
                              hipStream_t stream) {
  const float* hs      = (const float*)d_in[0];
  const float* q_a_w   = (const float*)d_in[1];
  const float* q_a_ln  = (const float*)d_in[2];
  const float* q_b_w   = (const float*)d_in[3];
  const float* kv_a_w  = (const float*)d_in[4];
  const float* kv_a_ln = (const float*)d_in[5];
  const float* kv_b_w  = (const float*)d_in[6];
  const float* o_w     = (const float*)d_in[7];
  float* out = (float*)d_out;
  char* ws = (char*)d_ws;

  u16* hid  = (u16*)(ws + 0);          // 16.78 MB  (B*T, 2048) bf16
  u16* wt   = (u16*)(ws + 16777216);   // 12.58 MB  transposed weight (reused)
  u16* qa   = (u16*)(ws + 29360128);   // 25.17 MB  fused a-out: [q_a 1536 | kv_raw 1536]
  u16* qan  = (u16*)(ws + 54525952);   // 12.58 MB  q_a normed (stride 1536)
  u16* qout = (u16*)(ws + 67108864);   // 25.17 MB  q (B*T, 16*192), pre-scaled
  u16* att  = (u16*)(ws + 92274688);   // 16.78 MB  attn out (B*T, 2048)
  u16* kv   = (u16*)(ws + 109051904);  // 33.55 MB  kv_b out (k_nope|v per head)
  u16* Vt   = (u16*)(ws + 142606336);  // 16.78 MB  (B,H,128,T)
  u16* qan2 = (u16*)(ws + 159383552);  //  4.19 MB  kv latent normed (stride 512)

  cast_f32_bf16<<<4096, 256, 0, stream>>>(hs, hid);

  // fused a-proj: [q_a | kv_raw] = hid @ [q_a_w | kv_a_w]   (256^2 pipeline)
  transpose_cast_k<<<dim3(1536 / 32, 2048 / 32), 256, 0, stream>>>(q_a_w, wt, 2048, 1536);
  transpose_cast_k<<<dim3(1536 / 32, 2048 / 32), 256, 0, stream>>>(kv_a_w, wt + (size_t)1536 * 2048, 2048, 1536);
  gemm256<1><<<(3072 / 256) * (4096 / 256), 512, 0, stream>>>(hid, wt, qa, nullptr, 4096, 3072, 2048);

  // both RMSNorms in one launch: q_a -> qan, kv latent -> qan2
  rmsnorm_dual<<<4096, 256, 0, stream>>>(qa, q_a_ln, qan, kv_a_ln, qan2);

  // q = qan @ q_b_w  (bf16, pre-scaled by log2e/sqrt(192))
  transpose_cast_k<<<dim3(3072 / 32, 1536 / 32), 256, 0, stream>>>(q_b_w, wt, 1536, 3072);
  gemm256<3><<<(3072 / 256) * (4096 / 256), 512, 0, stream>>>(qan, wt, qout, nullptr, 4096, 3072, 1536);

  // kv = qan2 @ kv_b_w  -> kv row-major + Vt scatter fused
  transpose_cast_k<<<dim3(4096 / 32, 512 / 32), 256, 0, stream>>>(kv_b_w, wt, 512, 4096);
  gemm256<2><<<(4096 / 256) * (4096 / 256), 512, 0, stream>>>(qan2, wt, kv, Vt, 4096, 4096, 512);

  // attention -> att   (r14-verified 64-key kernel, indexed staging)
  attn_k<<<512, 256, 0, stream>>>(qout, kv, qa, Vt, att);

  // out = att @ o_w   (r8-verified 128^2 kernel, f32 out)
  transpose_cast_k<<<dim3(2048 / 32, 2048 / 32), 256, 0, stream>>>(o_w, wt, 2048, 2048);
  gemm_bt<0><<<(2048 / 128) * (4096 / 128), 256, 0, stream>>>(att, wt, out, 4096, 2048, 2048);
}

// Round 18
// 307.720 us; speedup vs baseline: 1.0896x; 1.0153x over previous
//
#include <hip/hip_runtime.h>
#include <cstdint>
#include <cstddef>

typedef unsigned short u16;
typedef short short8 __attribute__((ext_vector_type(8)));
typedef float f32x4 __attribute__((ext_vector_type(4)));

#define B_   2
#define T_   2048
#define H_   16
#define HID_ 2048
#define DQK_ 192
#define DV_  128
#define AW_  3072   // fused a-proj output width (q_a 1536 | kv_raw 1536)

__device__ __forceinline__ float bf2f(u16 u) {
  unsigned int v = ((unsigned int)u) << 16;
  return __builtin_bit_cast(float, v);
}
__device__ __forceinline__ u16 f2bf(float f) {
  unsigned int u = __builtin_bit_cast(unsigned int, f);
  u += 0x7fff + ((u >> 16) & 1);   // round-to-nearest-even
  return (u16)(u >> 16);
}
__device__ __forceinline__ void load_lds16(const void* g, void* l) {
  __builtin_amdgcn_global_load_lds((const __attribute__((address_space(1))) void*)g,
                                   (__attribute__((address_space(3))) void*)l, 16, 0, 0);
}

// ---------------- cast f32 -> bf16 (8 elems/thread) ----------------
__global__ __launch_bounds__(256) void cast_f32_bf16(const float* __restrict__ x,
                                                     u16* __restrict__ y) {
  size_t i = ((size_t)blockIdx.x * 256 + threadIdx.x) * 8;
  float4 a = *(const float4*)&x[i];
  float4 b = *(const float4*)&x[i + 4];
  u16 r[8];
  r[0] = f2bf(a.x); r[1] = f2bf(a.y); r[2] = f2bf(a.z); r[3] = f2bf(a.w);
  r[4] = f2bf(b.x); r[5] = f2bf(b.y); r[6] = f2bf(b.z); r[7] = f2bf(b.w);
  *(uint4*)&y[i] = *(const uint4*)&r[0];
}

// ---------------- W (K x N) f32 -> Wt (N x K) bf16, vectorized ----------------
// 32k x 128n tile per block. Read: float4/lane (16B, fully coalesced; old
// version was 4B/lane scalar -- G13). Write: uint4/lane (16B). LDS 8.25KB
// round-trip (stride 132; read-back <=4-way, off the critical path).
__global__ __launch_bounds__(256) void transpose_cast_k(const float* __restrict__ W,
                                                        u16* __restrict__ Wt,
                                                        int K, int N) {
  __shared__ u16 tile[32][132];
  const int n0 = blockIdx.x * 128, k0 = blockIdx.y * 32;
  const int tx = threadIdx.x & 31, ty = threadIdx.x >> 5;   // 32 x 8
#pragma unroll
  for (int i = 0; i < 32; i += 8) {
    float4 v = *(const float4*)&W[(size_t)(k0 + ty + i) * N + n0 + tx * 4];
    u16 r4[4];
    r4[0] = f2bf(v.x); r4[1] = f2bf(v.y); r4[2] = f2bf(v.z); r4[3] = f2bf(v.w);
    *(uint2*)&tile[ty + i][tx * 4] = *(const uint2*)&r4[0];
  }
  __syncthreads();
#pragma unroll
  for (int c = 0; c < 2; ++c) {
    int idx = c * 256 + threadIdx.x;
    int n = idx >> 2, ck = idx & 3;
    u16 r8[8];
#pragma unroll
    for (int e = 0; e < 8; ++e) r8[e] = tile[ck * 8 + e][n];
    *(uint4*)&Wt[(size_t)(n0 + n) * K + k0 + ck * 8] = *(const uint4*)&r8[0];
  }
}

// ---------------- dual RMSNorm: q_a (L=1536) -> out1, kv latent (L=512) -> out2 ----------------
__global__ __launch_bounds__(256) void rmsnorm_dual(const u16* __restrict__ qa,
                                                    const float* __restrict__ w1,
                                                    u16* __restrict__ out1,
                                                    const float* __restrict__ w2,
                                                    u16* __restrict__ out2) {
  __shared__ float red[4];
  const int row = blockIdx.x, tid = threadIdx.x;
  {
    const u16* x = qa + (size_t)row * AW_;
    float ss = 0.f;
    for (int i = tid * 8; i < 1536; i += 2048) {
      uint4 v = *(const uint4*)&x[i];
      const u16* p = (const u16*)&v;
#pragma unroll
      for (int e = 0; e < 8; ++e) { float f = bf2f(p[e]); ss += f * f; }
    }
#pragma unroll
    for (int m = 32; m >= 1; m >>= 1) ss += __shfl_xor(ss, m);
    if ((tid & 63) == 0) red[tid >> 6] = ss;
    __syncthreads();
    ss = red[0] + red[1] + red[2] + red[3];
    float inv = rsqrtf(ss / 1536.f + 1e-6f);
    u16* o = out1 + (size_t)row * 1536;
    for (int i = tid * 8; i < 1536; i += 2048) {
      uint4 v = *(const uint4*)&x[i];
      const u16* p = (const u16*)&v;
      u16 r8[8];
#pragma unroll
      for (int e = 0; e < 8; ++e) r8[e] = f2bf(bf2f(p[e]) * inv * w1[i + e]);
      *(uint4*)&o[i] = *(const uint4*)&r8[0];
    }
  }
  __syncthreads();
  {
    const u16* x = qa + (size_t)row * AW_ + 1536;
    float ss = 0.f;
    for (int i = tid * 8; i < 512; i += 2048) {
      uint4 v = *(const uint4*)&x[i];
      const u16* p = (const u16*)&v;
#pragma unroll
      for (int e = 0; e < 8; ++e) { float f = bf2f(p[e]); ss += f * f; }
    }
#pragma unroll
    for (int m = 32; m >= 1; m >>= 1) ss += __shfl_xor(ss, m);
    if ((tid & 63) == 0) red[tid >> 6] = ss;
    __syncthreads();
    ss = red[0] + red[1] + red[2] + red[3];
    float inv = rsqrtf(ss / 512.f + 1e-6f);
    u16* o = out2 + (size_t)row * 512;
    for (int i = tid * 8; i < 512; i += 2048) {
      uint4 v = *(const uint4*)&x[i];
      const u16* p = (const u16*)&v;
      u16 r8[8];
#pragma unroll
      for (int e = 0; e < 8; ++e) r8[e] = f2bf(bf2f(p[e]) * inv * w2[i + e]);
      *(uint4*)&o[i] = *(const uint4*)&r8[0];
    }
  }
}

// ---------------- GEMM 256x256 (4-phase), BK=64, 512 thr / 8 waves ----------------
// Verified r14/r15/r17. EPI: 1 = bf16; 3 = bf16 * softmax scale; 2 = bf16 + Vt scatter.
template <int EPI>
__global__ __launch_bounds__(512) void gemm256(const u16* __restrict__ A,
                                               const u16* __restrict__ Bt,
                                               void* __restrict__ Cout,
                                               u16* __restrict__ Vt2,
                                               int M, int N, int K) {
  __shared__ u16 As[2][256 * 64];   // 64 KB
  __shared__ u16 Bs[2][256 * 64];   // 64 KB
  const int nbx = N >> 8;
  const int bx = blockIdx.x % nbx, by = blockIdx.x / nbx;
  const int m0 = by << 8, n0 = bx << 8;
  const int tid = threadIdx.x, w = tid >> 6, lane = tid & 63;
  const int wm = w >> 2, wn = w & 3;
  const int llo = lane & 15, lhi = lane >> 4;
  f32x4 acc[8][4] = {};

  const u16* srcp[8];
  int dsto[8];
#pragma unroll
  for (int jl = 0; jl < 2; ++jl) {
    int c = jl * 512 + tid;
    int i = c >> 3, sl = c & 7;
    { int r = ((i >> 6) << 7) + (i & 63);
      srcp[jl] = A + (size_t)(m0 + r) * K + ((sl ^ (r & 7)) << 3);
      dsto[jl] = (r * 8 + sl) * 8; }
    { int r = ((i >> 5) << 6) + (i & 31);
      srcp[2 + jl] = Bt + (size_t)(n0 + r) * K + ((sl ^ (r & 7)) << 3);
      dsto[2 + jl] = (r * 8 + sl) * 8; }
    { int r = ((i >> 5) << 6) + 32 + (i & 31);
      srcp[4 + jl] = Bt + (size_t)(n0 + r) * K + ((sl ^ (r & 7)) << 3);
      dsto[4 + jl] = (r * 8 + sl) * 8; }
    { int r = ((i >> 6) << 7) + 64 + (i & 63);
      srcp[6 + jl] = A + (size_t)(m0 + r) * K + ((sl ^ (r & 7)) << 3);
      dsto[6 + jl] = (r * 8 + sl) * 8; }
  }
#define STG(j, kt, buf)                                                        \
  load_lds16(srcp[j] + (size_t)(kt) * 64,                                      \
             ((j) < 2 || (j) >= 6) ? &As[(buf)][dsto[j]] : &Bs[(buf)][dsto[j]])

  auto rdA = [&](int buf, int mi, int ks) {
    int r = wm * 128 + mi * 16 + llo;
    return *(const short8*)&As[buf][r * 64 + (((ks * 4 + lhi) ^ (r & 7)) << 3)];
  };
  auto rdB = [&](int buf, int nj, int ks) {
    int r = wn * 64 + nj * 16 + llo;
    return *(const short8*)&Bs[buf][r * 64 + (((ks * 4 + lhi) ^ (r & 7)) << 3)];
  };

  const int NT = K >> 6;
#pragma unroll
  for (int j = 0; j < 8; ++j) STG(j, 0, 0);

  short8 af[4][2], bf[2][2];
  for (int kt = 0; kt < NT; ++kt) {
    const int cur = kt & 1, nxt = cur ^ 1;
    const bool hn = (kt + 1 < NT);
    asm volatile("s_waitcnt vmcnt(4)" ::: "memory");
    __builtin_amdgcn_s_barrier();
#pragma unroll
    for (int mi = 0; mi < 4; ++mi) { af[mi][0] = rdA(cur, mi, 0); af[mi][1] = rdA(cur, mi, 1); }
#pragma unroll
    for (int nj = 0; nj < 2; ++nj) { bf[nj][0] = rdB(cur, nj, 0); bf[nj][1] = rdB(cur, nj, 1); }
    if (hn) { STG(0, kt + 1, nxt); STG(1, kt + 1, nxt); }
    __builtin_amdgcn_s_setprio(1);
#pragma unroll
    for (int mi = 0; mi < 4; ++mi)
#pragma unroll
      for (int nj = 0; nj < 2; ++nj)
#pragma unroll
        for (int ks = 0; ks < 2; ++ks)
          acc[mi][nj] = __builtin_amdgcn_mfma_f32_16x16x32_bf16(af[mi][ks], bf[nj][ks], acc[mi][nj], 0, 0, 0);
    __builtin_amdgcn_s_setprio(0);
    if (hn) asm volatile("s_waitcnt vmcnt(4)" ::: "memory");
    else    asm volatile("s_waitcnt vmcnt(2)" ::: "memory");
    __builtin_amdgcn_s_barrier();
#pragma unroll
    for (int nj = 0; nj < 2; ++nj) { bf[nj][0] = rdB(cur, 2 + nj, 0); bf[nj][1] = rdB(cur, 2 + nj, 1); }
    if (hn) { STG(2, kt + 1, nxt); STG(3, kt + 1, nxt); }
    __builtin_amdgcn_s_setprio(1);
#pragma unroll
    for (int mi = 0; mi < 4; ++mi)
#pragma unroll
      for (int nj = 0; nj < 2; ++nj)
#pragma unroll
        for (int ks = 0; ks < 2; ++ks)
          acc[mi][2 + nj] = __builtin_amdgcn_mfma_f32_16x16x32_bf16(af[mi][ks], bf[nj][ks], acc[mi][2 + nj], 0, 0, 0);
    __builtin_amdgcn_s_setprio(0);
    if (hn) asm volatile("s_waitcnt vmcnt(4)" ::: "memory");
    else    asm volatile("s_waitcnt vmcnt(0)" ::: "memory");
    __builtin_amdgcn_s_barrier();
#pragma unroll
    for (int mi = 0; mi < 4; ++mi) { af[mi][0] = rdA(cur, 4 + mi, 0); af[mi][1] = rdA(cur, 4 + mi, 1); }
    if (hn) { STG(4, kt + 1, nxt); STG(5, kt + 1, nxt); }
    __builtin_amdgcn_s_setprio(1);
#pragma unroll
    for (int mi = 0; mi < 4; ++mi)
#pragma unroll
      for (int nj = 0; nj < 2; ++nj)
#pragma unroll
        for (int ks = 0; ks < 2; ++ks)
          acc[4 + mi][2 + nj] = __builtin_amdgcn_mfma_f32_16x16x32_bf16(af[mi][ks], bf[nj][ks], acc[4 + mi][2 + nj], 0, 0, 0);
    __builtin_amdgcn_s_setprio(0);
#pragma unroll
    for (int nj = 0; nj < 2; ++nj) { bf[nj][0] = rdB(cur, nj, 0); bf[nj][1] = rdB(cur, nj, 1); }
    if (hn) { STG(6, kt + 1, nxt); STG(7, kt + 1, nxt); }
    __builtin_amdgcn_s_setprio(1);
#pragma unroll
    for (int mi = 0; mi < 4; ++mi)
#pragma unroll
      for (int nj = 0; nj < 2; ++nj)
#pragma unroll
        for (int ks = 0; ks < 2; ++ks)
          acc[4 + mi][nj] = __builtin_amdgcn_mfma_f32_16x16x32_bf16(af[mi][ks], bf[nj][ks], acc[4 + mi][nj], 0, 0, 0);
    __builtin_amdgcn_s_setprio(0);
  }
#undef STG

  const float scale = (EPI == 3) ? 0.10412163f : 1.0f;  // log2(e)/sqrt(192)
  u16* C = (u16*)Cout;
#pragma unroll
  for (int mi = 0; mi < 8; ++mi)
#pragma unroll
    for (int nj = 0; nj < 4; ++nj) {
      u16 vals[4];
#pragma unroll
      for (int r = 0; r < 4; ++r) {
        vals[r] = f2bf(acc[mi][nj][r] * scale);
        C[(size_t)(m0 + wm * 128 + mi * 16 + lhi * 4 + r) * N + (n0 + wn * 64 + nj * 16 + llo)] =
            vals[r];
      }
      if constexpr (EPI == 2) {
        if (wn >= 2) {   // V half of the head: also scatter to Vt (B,H,128,T)
          const int n = n0 + wn * 64 + nj * 16 + llo;
          const int mb = m0 + wm * 128 + mi * 16 + lhi * 4;
          const int bb = mb >> 11, t = mb & 2047;
          const int h = n >> 8, d = (n & 255) - 128;
          *(uint2*)&Vt2[((size_t)((bb << 4) + h) * 128 + d) * (size_t)T_ + t] =
              *(const uint2*)&vals[0];
        }
      }
    }
}

// ---------------- GEMM 128x128 (r8-verified) — kept for o_w (f32 out) ----------------
template <int EPI>
__global__ __launch_bounds__(256) void gemm_bt(const u16* __restrict__ A,
                                               const u16* __restrict__ Bt,
                                               void* __restrict__ Cout,
                                               int M, int N, int K) {
  __shared__ u16 As[3][128 * 32];
  __shared__ u16 Bs[3][128 * 32];
  const int nbx = N >> 7;
  const int bx = blockIdx.x % nbx, by = blockIdx.x / nbx;
  const int m0 = by << 7, n0 = bx << 7;
  const int tid = threadIdx.x, w = tid >> 6, lane = tid & 63;
  const int wr = w >> 1, wc = w & 1;
  const int llo = lane & 15, lhi = lane >> 4;
  f32x4 acc[4][4] = {};

  const int c0 = tid, c1 = tid + 256;
  const int ar0 = c0 >> 2, s0_ = c0 & 3;
  const int ar1 = c1 >> 2, s1_ = c1 & 3;
  const u16* Asrc0 = A + (size_t)(m0 + ar0) * K + (s0_ ^ ((ar0 >> 1) & 3)) * 8;
  const u16* Asrc1 = A + (size_t)(m0 + ar1) * K + (s1_ ^ ((ar1 >> 1) & 3)) * 8;
  const u16* Bsrc0 = Bt + (size_t)(n0 + ar0) * K + (s0_ ^ ((ar0 >> 1) & 3)) * 8;
  const u16* Bsrc1 = Bt + (size_t)(n0 + ar1) * K + (s1_ ^ ((ar1 >> 1) & 3)) * 8;

  int aoff[4], boff[4];
#pragma unroll
  for (int i = 0; i < 4; ++i) {
    int rowa = wr * 64 + i * 16 + llo;
    aoff[i] = (rowa * 4 + (lhi ^ ((rowa >> 1) & 3))) * 8;
    int rowb = wc * 64 + i * 16 + llo;
    boff[i] = (rowb * 4 + (lhi ^ ((rowb >> 1) & 3))) * 8;
  }

#define STAGE_KT(kt, buf)                                   \
  do {                                                      \
    int k0_ = (kt) << 5;                                    \
    load_lds16(Asrc0 + k0_, &As[(buf)][c0 * 8]);            \
    load_lds16(Asrc1 + k0_, &As[(buf)][c1 * 8]);            \
    load_lds16(Bsrc0 + k0_, &Bs[(buf)][c0 * 8]);            \
    load_lds16(Bsrc1 + k0_, &Bs[(buf)][c1 * 8]);            \
  } while (0)

  const int NT = K >> 5;
  STAGE_KT(0, 0);
  STAGE_KT(1, 1);
  asm volatile("s_waitcnt vmcnt(4)" ::: "memory");
  __builtin_amdgcn_s_barrier();

  int cur = 0, nxt = 2;
  for (int kt = 0; kt < NT; ++kt) {
    if (kt + 2 < NT) STAGE_KT(kt + 2, nxt);
    short8 af[4], bfr[4];
#pragma unroll
    for (int i = 0; i < 4; ++i) af[i] = *(const short8*)&As[cur][aoff[i]];
#pragma unroll
    for (int j = 0; j < 4; ++j) bfr[j] = *(const short8*)&Bs[cur][boff[j]];
    __builtin_amdgcn_s_setprio(1);
#pragma unroll
    for (int i = 0; i < 4; ++i)
#pragma unroll
      for (int j = 0; j < 4; ++j)
        acc[i][j] = __builtin_amdgcn_mfma_f32_16x16x32_bf16(af[i], bfr[j], acc[i][j], 0, 0, 0);
    __builtin_amdgcn_s_setprio(0);
    if (kt + 2 < NT) asm volatile("s_waitcnt vmcnt(4)" ::: "memory");
    else             asm volatile("s_waitcnt vmcnt(0)" ::: "memory");
    __builtin_amdgcn_s_barrier();
    cur = (cur == 2) ? 0 : cur + 1;
    nxt = (nxt == 2) ? 0 : nxt + 1;
  }
#undef STAGE_KT

  if constexpr (EPI == 0) {
    float* C = (float*)Cout;
#pragma unroll
    for (int i = 0; i < 4; ++i)
#pragma unroll
      for (int j = 0; j < 4; ++j)
#pragma unroll
        for (int r = 0; r < 4; ++r)
          C[(size_t)(m0 + wr * 64 + i * 16 + lhi * 4 + r) * N + (n0 + wc * 64 + j * 16 + llo)] =
              acc[i][j][r];
  } else {
    u16* C = (u16*)Cout;
#pragma unroll
    for (int i = 0; i < 4; ++i)
#pragma unroll
      for (int j = 0; j < 4; ++j)
#pragma unroll
        for (int r = 0; r < 4; ++r)
          C[(size_t)(m0 + wr * 64 + i * 16 + lhi * 4 + r) * N + (n0 + wc * 64 + j * 16 + llo)] =
              f2bf(acc[i][j][r]);
  }
}

// ---------------- causal flash attention (r14/r17-verified: ~100us) ----------------
// block 256 (4 waves x 16 q-rows); k-tile 64; TWO passes (qt=31-pr, qt=pr) = 33
// k-tiles/block. xcd=p&7, bh=xcd*4+(j&3) -> 4 bh/XCD (FETCH 42MB, r11-verified).
// global_load_lds staging (indexed addressing), K dbuf, counted vmcnt,
// source-side XOR (rule #21), exp2 softmax, lazy row-max (T13), deferred
// l-reduce. LDS 72KB -> 2 blocks/CU. 4 structural variants lost to this shape.
__global__ __launch_bounds__(256, 2) void attn_k(const u16* __restrict__ q,
                                                 const u16* __restrict__ kv,
                                                 const u16* __restrict__ kvraw,
                                                 const u16* __restrict__ Vt,
                                                 u16* __restrict__ att) {
  constexpr int KLD = 192, VLD = 64, PLD = 64;
  __shared__ u16 Ks[2][64 * KLD];
  __shared__ u16 Vs[128 * VLD];
  __shared__ u16 Ps[64 * PLD];
  const int p = (int)blockIdx.x;
  const int xcd = p & 7, j = p >> 3;
  const int bh = xcd * 4 + (j & 3);   // 4 bh per XCD
  const int pr = j >> 2;              // 0..15
  const int b = bh >> 4, h = bh & 15;
  const int bT = b * T_;
  const int tid = threadIdx.x, w = tid >> 6, lane = tid & 63;
  const int llo = lane & 15, lhi = lane >> 4;
  const u16* Vb = Vt + (size_t)bh * DV_ * T_;

  const u16* kbase[6]; int kstr[6];
#pragma unroll
  for (int ii = 0; ii < 6; ++ii) {
    int c = ii * 256 + tid;
    int rr = c / 24, chk = c - rr * 24;
    int sc = chk ^ (rr & 7);
    if (sc < 16) { kbase[ii] = kv + (size_t)(bT + rr) * 4096 + h * 256 + sc * 8; kstr[ii] = 4096; }
    else { kbase[ii] = kvraw + (size_t)(bT + rr) * AW_ + 2048 + h * 64 + (sc - 16) * 8; kstr[ii] = AW_; }
  }
  int voff[4];
#pragma unroll
  for (int ii = 0; ii < 4; ++ii) {
    int c = ii * 256 + tid;
    int rr = c >> 3, chk = c & 7;
    voff[ii] = rr * T_ + (chk ^ (rr & 7)) * 8;
  }

#pragma unroll
  for (int pass = 0; pass < 2; ++pass) {
    const int qt = pass == 0 ? 31 - pr : pr;
    const int q0 = qt * 64;
    const int rbase = q0 + w * 16;
    short8 qf[6];
#pragma unroll
    for (int kk = 0; kk < 6; ++kk)
      qf[kk] = *(const short8*)&q[(size_t)(bT + rbase + llo) * AW_ + h * DQK_ + kk * 32 + lhi * 8];
    f32x4 oacc[8] = {};
    float m_r[4], l_r[4];
#pragma unroll
    for (int r = 0; r < 4; ++r) { m_r[r] = -1e30f; l_r[r] = 0.f; }

#pragma unroll
    for (int ii = 0; ii < 6; ++ii)
      load_lds16(kbase[ii], &Ks[0][(ii * 256 + tid) * 8]);
    asm volatile("s_waitcnt vmcnt(0)" ::: "memory");
    __builtin_amdgcn_s_barrier();
    __builtin_amdgcn_sched_barrier(0);

    const int nkt = qt + 1;
    int cur = 0;
    for (int kt = 0; kt < nkt; ++kt) {
      const int k0 = kt * 64;
      const bool hasNext = (kt + 1 < nkt);
#pragma unroll
      for (int ii = 0; ii < 4; ++ii)
        load_lds16(Vb + k0 + voff[ii], &Vs[(ii * 256 + tid) * 8]);
      if (hasNext) {
        u16* kd = Ks[cur ^ 1];
#pragma unroll
        for (int ii = 0; ii < 6; ++ii)
          load_lds16(kbase[ii] + (size_t)(k0 + 64) * kstr[ii], &kd[(ii * 256 + tid) * 8]);
      }
      const u16* kbuf = Ks[cur];
      f32x4 s[4] = {};
      __builtin_amdgcn_s_setprio(1);
#pragma unroll
      for (int kk = 0; kk < 6; ++kk) {
        const int col = kk * 32 + lhi * 8;
        short8 kf[4];
#pragma unroll
        for (int j2 = 0; j2 < 4; ++j2) {
          const int row = j2 * 16 + llo;
          kf[j2] = *(const short8*)&kbuf[row * KLD + (col ^ ((row & 7) << 3))];
        }
#pragma unroll
        for (int j2 = 0; j2 < 4; ++j2)
          s[j2] = __builtin_amdgcn_mfma_f32_16x16x32_bf16(qf[kk], kf[j2], s[j2], 0, 0, 0);
      }
      __builtin_amdgcn_s_setprio(0);
      const bool needMask = (k0 + 63 > rbase);
#pragma unroll
      for (int r = 0; r < 4; ++r) {
        const int qrow = rbase + lhi * 4 + r;
        float sv[4];
#pragma unroll
        for (int j2 = 0; j2 < 4; ++j2) {
          float x = s[j2][r];
          if (needMask) { int kcol = k0 + j2 * 16 + llo; x = (kcol <= qrow) ? x : -1e30f; }
          sv[j2] = x;
        }
        float mx4 = fmaxf(fmaxf(sv[0], sv[1]), fmaxf(sv[2], sv[3]));
        if (!__all(mx4 - m_r[r] <= 8.f)) {
          float mx = mx4;
#pragma unroll
          for (int mk = 1; mk < 16; mk <<= 1) mx = fmaxf(mx, __shfl_xor(mx, mk));
          float mnew = fmaxf(m_r[r], mx);
          float alpha = exp2f(m_r[r] - mnew);
          m_r[r] = mnew;
          l_r[r] *= alpha;
#pragma unroll
          for (int jo = 0; jo < 8; ++jo) oacc[jo][r] *= alpha;
        }
        float rs = 0.f;
        const int prow = w * 16 + lhi * 4 + r;
#pragma unroll
        for (int j2 = 0; j2 < 4; ++j2) {
          float p2 = exp2f(sv[j2] - m_r[r]);
          rs += p2;
          int pcol = j2 * 16 + llo;
          Ps[prow * PLD + (pcol ^ ((prow & 7) << 3))] = f2bf(p2);
        }
        l_r[r] += rs;
      }
      if (hasNext) asm volatile("s_waitcnt vmcnt(6)" ::: "memory");
      else         asm volatile("s_waitcnt vmcnt(0)" ::: "memory");
      __builtin_amdgcn_s_barrier();
      __builtin_amdgcn_sched_barrier(0);
      __builtin_amdgcn_s_setprio(1);
#pragma unroll
      for (int kk2 = 0; kk2 < 2; ++kk2) {
        const int prow = w * 16 + llo;
        const int pcol = kk2 * 32 + lhi * 8;
        short8 pf = *(const short8*)&Ps[prow * PLD + (pcol ^ ((prow & 7) << 3))];
#pragma unroll
        for (int jo = 0; jo < 8; ++jo) {
          const int vrow = jo * 16 + llo;
          short8 vf = *(const short8*)&Vs[vrow * VLD + (pcol ^ ((vrow & 7) << 3))];
          oacc[jo] = __builtin_amdgcn_mfma_f32_16x16x32_bf16(pf, vf, oacc[jo], 0, 0, 0);
        }
      }
      __builtin_amdgcn_s_setprio(0);
      asm volatile("s_waitcnt vmcnt(0)" ::: "memory");
      __builtin_amdgcn_s_barrier();
      __builtin_amdgcn_sched_barrier(0);
      cur ^= 1;
    }
#pragma unroll
    for (int r = 0; r < 4; ++r) {
      float lr = l_r[r];
#pragma unroll
      for (int mk = 1; mk < 16; mk <<= 1) lr += __shfl_xor(lr, mk);
      const int qrow = rbase + lhi * 4 + r;
      const float linv = 1.f / lr;
#pragma unroll
      for (int jo = 0; jo < 8; ++jo)
        att[((size_t)bT + qrow) * (H_ * DV_) + h * DV_ + jo * 16 + llo] =
            f2bf(oacc[jo][r] * linv);
    }
  }
}

// ---------------- launch ----------------
extern "C" void kernel_launch(void* const* d_in, const int* in_sizes, int n_in,
                              void* d_out, int out_size, void* d_ws, size_t ws_size,
                              hipStream_t stream) {
  const float* hs      = (const float*)d_in[0];
  const float* q_a_w   = (const float*)d_in[1];
  const float* q_a_ln  = (const float*)d_in[2];
  const float* q_b_w   = (const float*)d_in[3];
  const float* kv_a_w  = (const float*)d_in[4];
  const float* kv_a_ln = (const float*)d_in[5];
  const float* kv_b_w  = (const float*)d_in[6];
  const float* o_w     = (const float*)d_in[7];
  float* out = (float*)d_out;
  char* ws = (char*)d_ws;

  u16* hid  = (u16*)(ws + 0);          // 16.78 MB  (B*T, 2048) bf16
  u16* wt   = (u16*)(ws + 16777216);   // 12.58 MB  transposed weight (reused)
  u16* qa   = (u16*)(ws + 29360128);   // 25.17 MB  fused a-out: [q_a 1536 | kv_raw 1536]
  u16* qan  = (u16*)(ws + 54525952);   // 12.58 MB  q_a normed (stride 1536)
  u16* qout = (u16*)(ws + 67108864);   // 25.17 MB  q (B*T, 16*192), pre-scaled
  u16* att  = (u16*)(ws + 92274688);   // 16.78 MB  attn out (B*T, 2048)
  u16* kv   = (u16*)(ws + 109051904);  // 33.55 MB  kv_b out (k_nope|v per head)
  u16* Vt   = (u16*)(ws + 142606336);  // 16.78 MB  (B,H,128,T)
  u16* qan2 = (u16*)(ws + 159383552);  //  4.19 MB  kv latent normed (stride 512)

  cast_f32_bf16<<<4096, 256, 0, stream>>>(hs, hid);

  // fused a-proj: [q_a | kv_raw] = hid @ [q_a_w | kv_a_w]   (256^2 pipeline)
  transpose_cast_k<<<dim3(1536 / 128, 2048 / 32), 256, 0, stream>>>(q_a_w, wt, 2048, 1536);
  transpose_cast_k<<<dim3(1536 / 128, 2048 / 32), 256, 0, stream>>>(kv_a_w, wt + (size_t)1536 * 2048, 2048, 1536);
  gemm256<1><<<(3072 / 256) * (4096 / 256), 512, 0, stream>>>(hid, wt, qa, nullptr, 4096, 3072, 2048);

  // both RMSNorms in one launch: q_a -> qan, kv latent -> qan2
  rmsnorm_dual<<<4096, 256, 0, stream>>>(qa, q_a_ln, qan, kv_a_ln, qan2);

  // q = qan @ q_b_w  (bf16, pre-scaled by log2e/sqrt(192))
  transpose_cast_k<<<dim3(3072 / 128, 1536 / 32), 256, 0, stream>>>(q_b_w, wt, 1536, 3072);
  gemm256<3><<<(3072 / 256) * (4096 / 256), 512, 0, stream>>>(qan, wt, qout, nullptr, 4096, 3072, 1536);

  // kv = qan2 @ kv_b_w  -> kv row-major + Vt scatter fused
  transpose_cast_k<<<dim3(4096 / 128, 512 / 32), 256, 0, stream>>>(kv_b_w, wt, 512, 4096);
  gemm256<2><<<(4096 / 256) * (4096 / 256), 512, 0, stream>>>(qan2, wt, kv, Vt, 4096, 4096, 512);

  // attention -> att   (r14-verified 64-key kernel)
  attn_k<<<512, 256, 0, stream>>>(qout, kv, qa, Vt, att);

  // out = att @ o_w   (r8-verified 128^2 kernel, f32 out)
  transpose_cast_k<<<dim3(2048 / 128, 2048 / 32), 256, 0, stream>>>(o_w, wt, 2048, 2048);
  gemm_bt<0><<<(2048 / 128) * (4096 / 128), 256, 0, stream>>>(att, wt, out, 4096, 2048, 2048);
}